// Round 8
// baseline (164.455 us; speedup 1.0000x reference)
//
#include <hip/hip_runtime.h>

// SignSemanticsAggregator on MI355X (gfx950), round 8.
// E = sp + 32*sn (i8); E@E digits: M_same=(acc&31)+(acc>>10), M_diff=(acc>>5)&31.
// Round-8: BARRIER-FREE K-loop — each wave owns a private 2-buf LDS pipeline
// (stages its own 64x64 A/B halves via global_load_lds, counted vmcnt(8)),
// so no __syncthreads at all; slimmer preamble (4-mask scatter, fused
// build E + ballot-transposed ET in one kernel).

#define NN 4096
#define NW 128
#define MASK_BYTES ((size_t)NN * NW * 4)     // 2 MiB per mask
#define MASK_WORDS ((size_t)NN * NW)

typedef unsigned int u32;
typedef __attribute__((ext_vector_type(4))) int int4v;
typedef __attribute__((ext_vector_type(4))) float f32x4;

__device__ __forceinline__ void gload_lds16(const char* g, char* l) {
    __builtin_amdgcn_global_load_lds(
        (const __attribute__((address_space(1))) void*)g,
        (__attribute__((address_space(3))) void*)l, 16, 0, 0);
}

// ---------------- preprocessing ----------------

// 4 scatter targets (Pt, P1, Nt, N1). ~800K atomics total.
__global__ void scatter_all(const int* __restrict__ e0, const int* __restrict__ e1,
                            const int* __restrict__ e2, const int* __restrict__ e3,
                            int E0, int E1, int E2, int E3,
                            u32* __restrict__ ws) {
    int i = blockIdx.x * blockDim.x + threadIdx.x;
    u32* Pt = ws + 0 * MASK_WORDS;
    u32* P1 = ws + 1 * MASK_WORDS;
    u32* Nt = ws + 2 * MASK_WORDS;
    u32* N1 = ws + 3 * MASK_WORDS;
    if (i < E0) { int r = e0[i], c = e0[i + E0];
        atomicOr(&Pt[r * NW + (c >> 5)], 1u << (c & 31)); }
    if (i < E1) { int r = e1[i], c = e1[i + E1];
        atomicOr(&P1[r * NW + (c >> 5)], 1u << (c & 31)); }
    if (i < E2) { int r = e2[i], c = e2[i + E2];
        atomicOr(&Nt[r * NW + (c >> 5)], 1u << (c & 31)); }
    if (i < E3) { int r = e3[i], c = e3[i + E3];
        atomicOr(&N1[r * NW + (c >> 5)], 1u << (c & 31)); }
}

// Expand 16 mask bits (sp, sn) -> 16 i8 of E = sp + 32*sn.
__device__ __forceinline__ int4v expand_e(u32 sp, u32 sn) {
    int4v E;
    #pragma unroll
    for (int i = 0; i < 4; i++) {
        u32 p = (((sp >> (4 * i)) & 0xFu) * 0x00204081u) & 0x01010101u;
        u32 n = (((sn >> (4 * i)) & 0xFu) * 0x00204081u) & 0x01010101u;
        E[i] = (int)(p | (n << 5));
    }
    return E;
}

// One kernel: blocks [0,2048) build E row-wise from P1/N1; blocks [2048,4096)
// build ET via in-wave ballot bit-transpose (wave handles a 64x32 bit block).
// Pos-priority (n & ~p) and diagonal clearing applied in both halves.
__global__ void build_both(const u32* __restrict__ masks,
                           char* __restrict__ E, char* __restrict__ ET) {
    const u32* P  = masks + 1 * MASK_WORDS;
    const u32* Nm = masks + 3 * MASK_WORDS;
    if (blockIdx.x < 2048) {
        int w = blockIdx.x * 256 + threadIdx.x;      // word index a*128 + col
        u32 p = P[w];
        u32 n = Nm[w] & ~p;
        int a = w >> 7, col = w & 127;
        if ((a >> 5) == col) {
            u32 db = 1u << (a & 31);
            p &= ~db; n &= ~db;
        }
        char* dst = E + (size_t)a * NN + col * 32;
        *reinterpret_cast<int4v*>(dst)      = expand_e(p & 0xFFFFu, n & 0xFFFFu);
        *reinterpret_cast<int4v*>(dst + 16) = expand_e(p >> 16, n >> 16);
    } else {
        int gw = (blockIdx.x - 2048) * 4 + (threadIdx.x >> 6);  // 8192 waves
        int lane = threadIdx.x & 63;
        int ab = gw >> 7;        // 64-row block of a
        int wc = gw & 127;       // word column (c-block of 32)
        u32 pw = P[(ab * 64 + lane) * NW + wc];
        u32 nw = Nm[(ab * 64 + lane) * NW + wc];
        u32 myp = 0, myn = 0;
        #pragma unroll
        for (int j = 0; j < 32; j++) {
            unsigned long long bp = __ballot((pw >> j) & 1u);
            unsigned long long bn = __ballot((nw >> j) & 1u);
            if ((lane & 31) == j) {
                myp = (lane < 32) ? (u32)bp : (u32)(bp >> 32);
                myn = (lane < 32) ? (u32)bn : (u32)(bn >> 32);
            }
        }
        u32 p = myp;
        u32 n = myn & ~p;
        int c = wc * 32 + (lane & 31);
        int abase = ab * 64 + (lane >> 5) * 32;
        if (c >= abase && c < abase + 32) {          // clear diagonal a == c
            u32 db = 1u << (c - abase);
            p &= ~db; n &= ~db;
        }
        char* dst = ET + (size_t)c * NN + abase;
        *reinterpret_cast<int4v*>(dst)      = expand_e(p & 0xFFFFu, n & 0xFFFFu);
        *reinterpret_cast<int4v*>(dst + 16) = expand_e(p >> 16, n >> 16);
    }
}

// ---------------- fused GEMM + epilogue (barrier-free) ----------------
// Grid = 528 upper-tri 128x128 tiles. Each of the 4 waves owns a 64x64
// output sub-tile AND a private 2-buf LDS pipeline staging exactly the
// A-half / B-half it reads. No __syncthreads anywhere.
__global__ __launch_bounds__(256, 2) void gemm_ep(
    const char* __restrict__ E, const char* __restrict__ ET,
    const u32* __restrict__ Pt, const u32* __restrict__ P1,
    const u32* __restrict__ Nt, const u32* __restrict__ N1,
    float* __restrict__ out)
{
    const int tid = threadIdx.x;
    const size_t plane = (size_t)NN * NN;

    // triangular tile map with bijective XCD swizzle (528 = 8 * 66)
    int s_ = ((int)blockIdx.x & 7) * 66 + ((int)blockIdx.x >> 3);
    int by = (int)((65.0f - sqrtf(4225.0f - 8.0f * (float)s_)) * 0.5f);
    if (by > 31) by = 31;
    while (by > 0 && 32 * by - (by * (by - 1)) / 2 > s_) --by;
    while (32 * (by + 1) - ((by + 1) * by) / 2 <= s_) ++by;
    int bx = by + s_ - (32 * by - (by * (by - 1)) / 2);
    const int a0 = by << 7, c0 = bx << 7;

    // [wave][buf][ A: 0..4095 | B: 4096..8191 ]  — 64 KB total
    __shared__ char LB[4][2][8192];

    const int wave = tid >> 6, lane = tid & 63;
    const int wr = (wave >> 1) * 64, wcol = (wave & 1) * 64;
    const int lr = lane & 15, lg = lane >> 4;
    const int ko = (lg ^ ((lr >> 1) & 3)) << 4;    // read-side swizzle offset

    // staging source: lane covers row (lane>>2) of each 16-row group,
    // 16-B chunk (lane&3), source chunk pre-swizzled by ((lane>>3)&3)
    // (= ((row)>>1)&3 for row = 16*i + (lane>>2), any i).
    const int sswz = ((lane & 3) ^ ((lane >> 3) & 3)) << 4;
    const char* gA = E  + (size_t)(a0 + wr   + (lane >> 2)) * NN + sswz;
    const char* gB = ET + (size_t)(c0 + wcol + (lane >> 2)) * NN + sswz;

    int4v acc[4][4];
    int4v zero = {0, 0, 0, 0};
    #pragma unroll
    for (int m = 0; m < 4; m++)
        #pragma unroll
        for (int n = 0; n < 4; n++) acc[m][n] = zero;

    #define STAGE(b, t)                                                \
        do {                                                           \
            const int _kf = (t) * 64;                                  \
            gload_lds16(gA + _kf,          &LB[wave][b][0]);           \
            gload_lds16(gA + 65536 + _kf,  &LB[wave][b][1024]);        \
            gload_lds16(gA + 131072 + _kf, &LB[wave][b][2048]);        \
            gload_lds16(gA + 196608 + _kf, &LB[wave][b][3072]);        \
            gload_lds16(gB + _kf,          &LB[wave][b][4096]);        \
            gload_lds16(gB + 65536 + _kf,  &LB[wave][b][5120]);        \
            gload_lds16(gB + 131072 + _kf, &LB[wave][b][6144]);        \
            gload_lds16(gB + 196608 + _kf, &LB[wave][b][7168]);        \
        } while (0)

    #define FRAGS(b)                                                   \
        int4v af[4], bf[4];                                            \
        _Pragma("unroll")                                              \
        for (int n = 0; n < 4; n++)                                    \
            bf[n] = *reinterpret_cast<const int4v*>(                   \
                &LB[wave][b][4096 + (n * 16 + lr) * 64 + ko]);         \
        _Pragma("unroll")                                              \
        for (int m = 0; m < 4; m++)                                    \
            af[m] = *reinterpret_cast<const int4v*>(                   \
                &LB[wave][b][(m * 16 + lr) * 64 + ko]);

    #define MFMAS()                                                    \
        __builtin_amdgcn_s_setprio(1);                                 \
        _Pragma("unroll")                                              \
        for (int m = 0; m < 4; m++)                                    \
            _Pragma("unroll")                                          \
            for (int n = 0; n < 4; n++)                                \
                acc[m][n] = __builtin_amdgcn_mfma_i32_16x16x64_i8(     \
                    af[m], bf[n], acc[m][n], 0, 0, 0);                 \
        __builtin_amdgcn_s_setprio(0);

    // prologue: two buffers in flight (16 loads)
    STAGE(0, 0);
    STAGE(1, 1);

    for (int t = 0; t < 62; ++t) {
        const int cur = t & 1;
        asm volatile("s_waitcnt vmcnt(8)" ::: "memory");   // buf[cur] ready
        FRAGS(cur);
        asm volatile("s_waitcnt lgkmcnt(0)" ::: "memory"); // frags in regs
        __builtin_amdgcn_sched_barrier(0);
        STAGE(cur, t + 2);                                 // overwrite, WAR-safe
        MFMAS();
    }
    {   // t = 62
        asm volatile("s_waitcnt vmcnt(8)" ::: "memory");
        FRAGS(0);
        asm volatile("s_waitcnt lgkmcnt(0)" ::: "memory");
        MFMAS();
    }
    {   // t = 63
        asm volatile("s_waitcnt vmcnt(0)" ::: "memory");
        FRAGS(1);
        asm volatile("s_waitcnt lgkmcnt(0)" ::: "memory");
        MFMAS();
    }
    #undef STAGE
    #undef FRAGS
    #undef MFMAS

    // ---- fused epilogue: C/D layout col=lane&15, row=(lane>>4)*4+q ----
    #pragma unroll
    for (int m = 0; m < 4; m++) {
        #pragma unroll
        for (int n = 0; n < 4; n++) {
            #pragma unroll
            for (int q = 0; q < 4; q++) {
                int a = a0 + wr + m * 16 + lg * 4 + q;
                int c = c0 + wcol + n * 16 + lr;
                int widx = a * NW + (c >> 5);
                int bit = c & 31;
                u32 p1 = (P1[widx] >> bit) & 1u;
                u32 n1 = (N1[widx] >> bit) & 1u;
                u32 pt = (Pt[widx] >> bit) & 1u;
                u32 nt = (Nt[widx] >> bit) & 1u;
                int av = acc[m][n][q];
                int Ms = (av & 31) + (av >> 10);     // d0 + d2
                int Md = (av >> 5) & 31;             // d1
                int o0 = (int)(pt ^ p1) + ((a < c && !p1) ? Ms : 0);
                int o1 = (int)(nt ^ n1) + ((a < c && !n1) ? Md : 0);
                size_t oi = (size_t)a * NN + c;
                out[oi] = (float)o0;
                out[plane + oi] = (float)o1;
            }
        }
    }

    // ---- mirror tile xor (strictly-lower mirror), fire-and-forget ----
    if (by != bx) {
        #pragma unroll 4
        for (int pass = 0; pass < 16; ++pass) {
            int e = pass * 1024 + tid * 4;       // element in 128x128 tile
            int r = e >> 7, cc = e & 127;
            int widx = (c0 + r) * NW + ((a0 + cc) >> 5);
            int sh = cc & 31;
            u32 xp = (P1[widx] ^ Pt[widx]) >> sh;
            u32 xn = (N1[widx] ^ Nt[widx]) >> sh;
            f32x4 o0, o1;
            #pragma unroll
            for (int i = 0; i < 4; i++) {
                o0[i] = (float)((xp >> i) & 1u);
                o1[i] = (float)((xn >> i) & 1u);
            }
            size_t ob = (size_t)(c0 + r) * NN + a0 + cc;
            *reinterpret_cast<f32x4*>(out + ob) = o0;
            *reinterpret_cast<f32x4*>(out + plane + ob) = o1;
        }
    }
}

extern "C" void kernel_launch(void* const* d_in, const int* in_sizes, int n_in,
                              void* d_out, int out_size, void* d_ws, size_t ws_size,
                              hipStream_t stream) {
    char* ws = (char*)d_ws;
    u32* masks = (u32*)ws;                    // Pt,P1,Nt,N1 (4 x 2 MiB)
    u32* Pt = masks + 0 * MASK_WORDS;
    u32* P1 = masks + 1 * MASK_WORDS;
    u32* Nt = masks + 2 * MASK_WORDS;
    u32* N1 = masks + 3 * MASK_WORDS;
    char* E  = ws + 4 * MASK_BYTES;           // 16 MiB, linear
    char* ET = E + (size_t)NN * NN;           // 16 MiB, linear
    // ws use: 8 MiB masks + 32 MiB E/ET = 40 MiB

    hipMemsetAsync(d_ws, 0, 4 * MASK_BYTES, stream);

    // input order: A_pos_t, A_pos_tp1, A_neg_t, A_neg_tp1
    int E0 = in_sizes[0] / 2, E1 = in_sizes[1] / 2;
    int E2 = in_sizes[2] / 2, E3 = in_sizes[3] / 2;
    int Emax = max(max(E0, E1), max(E2, E3));
    scatter_all<<<(Emax + 255) / 256, 256, 0, stream>>>(
        (const int*)d_in[0], (const int*)d_in[1], (const int*)d_in[2],
        (const int*)d_in[3], E0, E1, E2, E3, masks);

    build_both<<<4096, 256, 0, stream>>>(masks, E, ET);

    gemm_ep<<<528, 256, 0, stream>>>(E, ET, Pt, P1, Nt, N1, (float*)d_out);
}

// Round 9
// 150.140 us; speedup vs baseline: 1.0953x; 1.0953x over previous
//
#include <hip/hip_runtime.h>

// SignSemanticsAggregator on MI355X (gfx950), round 9.
// E = sp + 32*sn (i8); E@E digits: M_same=(acc&31)+(acc>>10), M_diff=(acc>>5)&31.
// Round-9: R7's shared-LDS triple-buffered counted-vmcnt K-loop, but with
// 64x128 rectangular tiles -> 1056 heavy blocks (4 blocks/CU resident,
// 36 KB LDS) for latency hiding; R8's slim preamble (4-mask scatter,
// fused build E + ballot-transposed ET).

#define NN 4096
#define NW 128
#define MASK_BYTES ((size_t)NN * NW * 4)     // 2 MiB per mask
#define MASK_WORDS ((size_t)NN * NW)

typedef unsigned int u32;
typedef __attribute__((ext_vector_type(4))) int int4v;
typedef __attribute__((ext_vector_type(4))) float f32x4;

__device__ __forceinline__ void gload_lds16(const char* g, char* l) {
    __builtin_amdgcn_global_load_lds(
        (const __attribute__((address_space(1))) void*)g,
        (__attribute__((address_space(3))) void*)l, 16, 0, 0);
}

// ---------------- preprocessing ----------------

__global__ void scatter_all(const int* __restrict__ e0, const int* __restrict__ e1,
                            const int* __restrict__ e2, const int* __restrict__ e3,
                            int E0, int E1, int E2, int E3,
                            u32* __restrict__ ws) {
    int i = blockIdx.x * blockDim.x + threadIdx.x;
    u32* Pt = ws + 0 * MASK_WORDS;
    u32* P1 = ws + 1 * MASK_WORDS;
    u32* Nt = ws + 2 * MASK_WORDS;
    u32* N1 = ws + 3 * MASK_WORDS;
    if (i < E0) { int r = e0[i], c = e0[i + E0];
        atomicOr(&Pt[r * NW + (c >> 5)], 1u << (c & 31)); }
    if (i < E1) { int r = e1[i], c = e1[i + E1];
        atomicOr(&P1[r * NW + (c >> 5)], 1u << (c & 31)); }
    if (i < E2) { int r = e2[i], c = e2[i + E2];
        atomicOr(&Nt[r * NW + (c >> 5)], 1u << (c & 31)); }
    if (i < E3) { int r = e3[i], c = e3[i + E3];
        atomicOr(&N1[r * NW + (c >> 5)], 1u << (c & 31)); }
}

// Expand 16 mask bits (sp, sn) -> 16 i8 of E = sp + 32*sn.
__device__ __forceinline__ int4v expand_e(u32 sp, u32 sn) {
    int4v E;
    #pragma unroll
    for (int i = 0; i < 4; i++) {
        u32 p = (((sp >> (4 * i)) & 0xFu) * 0x00204081u) & 0x01010101u;
        u32 n = (((sn >> (4 * i)) & 0xFu) * 0x00204081u) & 0x01010101u;
        E[i] = (int)(p | (n << 5));
    }
    return E;
}

// Blocks [0,2048): E row-wise from P1/N1. Blocks [2048,4096): ET via in-wave
// ballot bit-transpose. Pos-priority and diagonal clearing in both halves.
__global__ void build_both(const u32* __restrict__ masks,
                           char* __restrict__ E, char* __restrict__ ET) {
    const u32* P  = masks + 1 * MASK_WORDS;
    const u32* Nm = masks + 3 * MASK_WORDS;
    if (blockIdx.x < 2048) {
        int w = blockIdx.x * 256 + threadIdx.x;      // word index a*128 + col
        u32 p = P[w];
        u32 n = Nm[w] & ~p;
        int a = w >> 7, col = w & 127;
        if ((a >> 5) == col) {
            u32 db = 1u << (a & 31);
            p &= ~db; n &= ~db;
        }
        char* dst = E + (size_t)a * NN + col * 32;
        *reinterpret_cast<int4v*>(dst)      = expand_e(p & 0xFFFFu, n & 0xFFFFu);
        *reinterpret_cast<int4v*>(dst + 16) = expand_e(p >> 16, n >> 16);
    } else {
        int gw = (blockIdx.x - 2048) * 4 + (threadIdx.x >> 6);  // 8192 waves
        int lane = threadIdx.x & 63;
        int ab = gw >> 7;        // 64-row block of a
        int wc = gw & 127;       // word column (c-block of 32)
        u32 pw = P[(ab * 64 + lane) * NW + wc];
        u32 nw = Nm[(ab * 64 + lane) * NW + wc];
        u32 myp = 0, myn = 0;
        #pragma unroll
        for (int j = 0; j < 32; j++) {
            unsigned long long bp = __ballot((pw >> j) & 1u);
            unsigned long long bn = __ballot((nw >> j) & 1u);
            if ((lane & 31) == j) {
                myp = (lane < 32) ? (u32)bp : (u32)(bp >> 32);
                myn = (lane < 32) ? (u32)bn : (u32)(bn >> 32);
            }
        }
        u32 p = myp;
        u32 n = myn & ~p;
        int c = wc * 32 + (lane & 31);
        int abase = ab * 64 + (lane >> 5) * 32;
        if (c >= abase && c < abase + 32) {          // clear diagonal a == c
            u32 db = 1u << (c - abase);
            p &= ~db; n &= ~db;
        }
        char* dst = ET + (size_t)c * NN + abase;
        *reinterpret_cast<int4v*>(dst)      = expand_e(p & 0xFFFFu, n & 0xFFFFu);
        *reinterpret_cast<int4v*>(dst + 16) = expand_e(p >> 16, n >> 16);
    }
}

// ---------------- fused GEMM + epilogue ----------------
// Grid = 1056 tiles of 64(rows a) x 128(cols c) covering {tile ∩ upper-tri}:
// i <= 2j+1 for a-tile i, c-tile j. BK=64, 64 K-steps, shared LDS triple
// buffer, counted vmcnt(3), one barrier per step. Mirror-xor for lower
// triangle with epilogue-covered guard.
__global__ __launch_bounds__(256, 4) void gemm_ep(
    const char* __restrict__ E, const char* __restrict__ ET,
    const u32* __restrict__ Pt, const u32* __restrict__ P1,
    const u32* __restrict__ Nt, const u32* __restrict__ N1,
    float* __restrict__ out)
{
    const int tid = threadIdx.x;
    const size_t plane = (size_t)NN * NN;

    // triangular tile map with bijective XCD swizzle (1056 = 8 * 132)
    int s_ = ((int)blockIdx.x & 7) * 132 + ((int)blockIdx.x >> 3);
    // j = floor((-1+sqrt(1+4s))/2); offset(j) = j*j+j; i = s - offset
    int j = (int)((sqrtf(4.0f * (float)s_ + 1.0f) - 1.0f) * 0.5f);
    if (j > 31) j = 31;
    while (j > 0 && j * j + j > s_) --j;
    while ((j + 1) * (j + 1) + (j + 1) <= s_) ++j;
    int i = s_ - (j * j + j);
    const int a0 = i << 6, c0 = j << 7;

    // [buf][ A: 0..4095 | B: 4096..12287 ]  — 3 x 12 KB = 36 KB
    __shared__ char LB[3][12288];

    const int wave = tid >> 6, lane = tid & 63;
    const int wrr = (wave >> 1) * 32, wcc = (wave & 1) * 64;
    const int lr = lane & 15, lg = lane >> 4;

    // staging: thread covers row (tid>>2), chunk (tid&3); source chunk
    // pre-swizzled by ((row>>1)&3).
    const int srow = tid >> 2, sch = tid & 3;
    const int sswz = (sch ^ ((srow >> 1) & 3)) << 4;
    const char* gA  = E  + (size_t)(a0 + srow) * NN + sswz;
    const char* gB0 = ET + (size_t)(c0 + srow) * NN + sswz;
    const char* gB1 = gB0 + (size_t)64 * NN;
    const int l16 = tid * 16;

    int4v acc[2][4];
    int4v zero = {0, 0, 0, 0};
    #pragma unroll
    for (int m = 0; m < 2; m++)
        #pragma unroll
        for (int n = 0; n < 4; n++) acc[m][n] = zero;

    #define STAGE(b, t)                                       \
        do {                                                  \
            const int _kf = (t) * 64;                         \
            gload_lds16(gA  + _kf, &LB[b][l16]);              \
            gload_lds16(gB0 + _kf, &LB[b][4096 + l16]);       \
            gload_lds16(gB1 + _kf, &LB[b][8192 + l16]);       \
        } while (0)

    #define COMPUTE(b)                                                         \
        do {                                                                   \
            int4v bf[4];                                                       \
            _Pragma("unroll")                                                  \
            for (int n = 0; n < 4; n++) {                                      \
                int rowb = wcc + n * 16 + lr;                                  \
                bf[n] = *reinterpret_cast<const int4v*>(                       \
                    &LB[b][4096 + rowb * 64 + ((lg ^ ((rowb >> 1) & 3)) << 4)]); \
            }                                                                  \
            __builtin_amdgcn_s_setprio(1);                                     \
            _Pragma("unroll")                                                  \
            for (int m = 0; m < 2; m++) {                                      \
                int rowa = wrr + m * 16 + lr;                                  \
                int4v af = *reinterpret_cast<const int4v*>(                    \
                    &LB[b][rowa * 64 + ((lg ^ ((rowa >> 1) & 3)) << 4)]);      \
                _Pragma("unroll")                                              \
                for (int n = 0; n < 4; n++)                                    \
                    acc[m][n] = __builtin_amdgcn_mfma_i32_16x16x64_i8(         \
                        af, bf[n], acc[m][n], 0, 0, 0);                        \
            }                                                                  \
            __builtin_amdgcn_s_setprio(0);                                     \
        } while (0)

    // prologue: stage t=0,1 (6 loads in flight), wait for t=0's three.
    STAGE(0, 0);
    STAGE(1, 1);
    asm volatile("s_waitcnt vmcnt(3)" ::: "memory");
    __builtin_amdgcn_s_barrier();

    int cur = 0;
    for (int t = 0; t < 62; ++t) {
        int nb = cur + 2; if (nb >= 3) nb -= 3;
        STAGE(nb, t + 2);                    // 3 loads -> outstanding 6
        COMPUTE(cur);
        asm volatile("s_waitcnt vmcnt(3)" ::: "memory");   // t+1 staged
        __builtin_amdgcn_s_barrier();
        cur = (cur == 2) ? 0 : cur + 1;
    }
    COMPUTE(cur);                            // t = 62 (buf 2)
    asm volatile("s_waitcnt vmcnt(0)" ::: "memory");       // t = 63 staged
    __builtin_amdgcn_s_barrier();
    cur = (cur == 2) ? 0 : cur + 1;
    COMPUTE(cur);                            // t = 63 (buf 0)
    #undef STAGE
    #undef COMPUTE

    // ---- fused epilogue: C/D layout col=lane&15, row=(lane>>4)*4+q ----
    #pragma unroll
    for (int m = 0; m < 2; m++) {
        #pragma unroll
        for (int n = 0; n < 4; n++) {
            #pragma unroll
            for (int q = 0; q < 4; q++) {
                int a = a0 + wrr + m * 16 + lg * 4 + q;
                int c = c0 + wcc + n * 16 + lr;
                int widx = a * NW + (c >> 5);
                int bit = c & 31;
                u32 p1 = (P1[widx] >> bit) & 1u;
                u32 n1 = (N1[widx] >> bit) & 1u;
                u32 pt = (Pt[widx] >> bit) & 1u;
                u32 nt = (Nt[widx] >> bit) & 1u;
                int av = acc[m][n][q];
                int Ms = (av & 31) + (av >> 10);     // d0 + d2
                int Md = (av >> 5) & 31;             // d1
                int o0 = (int)(pt ^ p1) + ((a < c && !p1) ? Ms : 0);
                int o1 = (int)(nt ^ n1) + ((a < c && !n1) ? Md : 0);
                size_t oi = (size_t)a * NN + c;
                out[oi] = (float)o0;
                out[plane + oi] = (float)o1;
            }
        }
    }

    // ---- mirror xor: rows [c0,c0+128) x cols [a0,a0+64) of the lower
    // triangle, skipping cells already covered by some epilogue tile
    // (cell (R,C) is epilogue-covered iff (R>>6) <= 2*(C>>7)+1).
    {
        #pragma unroll 4
        for (int pass = 0; pass < 8; ++pass) {
            int e = pass * 1024 + tid * 4;       // element in 128x64 mirror
            int rr = e >> 6, cc4 = e & 63;
            int R = c0 + rr, C = a0 + cc4;
            if ((R >> 6) <= 2 * (C >> 7) + 1) continue;   // epilogue-covered
            int widx = R * NW + (C >> 5);
            int sh = C & 31;
            u32 xp = (P1[widx] ^ Pt[widx]) >> sh;
            u32 xn = (N1[widx] ^ Nt[widx]) >> sh;
            f32x4 o0, o1;
            #pragma unroll
            for (int v = 0; v < 4; v++) {
                o0[v] = (float)((xp >> v) & 1u);
                o1[v] = (float)((xn >> v) & 1u);
            }
            size_t ob = (size_t)R * NN + C;
            *reinterpret_cast<f32x4*>(out + ob) = o0;
            *reinterpret_cast<f32x4*>(out + plane + ob) = o1;
        }
    }
}

extern "C" void kernel_launch(void* const* d_in, const int* in_sizes, int n_in,
                              void* d_out, int out_size, void* d_ws, size_t ws_size,
                              hipStream_t stream) {
    char* ws = (char*)d_ws;
    u32* masks = (u32*)ws;                    // Pt,P1,Nt,N1 (4 x 2 MiB)
    u32* Pt = masks + 0 * MASK_WORDS;
    u32* P1 = masks + 1 * MASK_WORDS;
    u32* Nt = masks + 2 * MASK_WORDS;
    u32* N1 = masks + 3 * MASK_WORDS;
    char* E  = ws + 4 * MASK_BYTES;           // 16 MiB, linear
    char* ET = E + (size_t)NN * NN;           // 16 MiB, linear
    // ws use: 8 MiB masks + 32 MiB E/ET = 40 MiB

    hipMemsetAsync(d_ws, 0, 4 * MASK_BYTES, stream);

    // input order: A_pos_t, A_pos_tp1, A_neg_t, A_neg_tp1
    int E0 = in_sizes[0] / 2, E1 = in_sizes[1] / 2;
    int E2 = in_sizes[2] / 2, E3 = in_sizes[3] / 2;
    int Emax = max(max(E0, E1), max(E2, E3));
    scatter_all<<<(Emax + 255) / 256, 256, 0, stream>>>(
        (const int*)d_in[0], (const int*)d_in[1], (const int*)d_in[2],
        (const int*)d_in[3], E0, E1, E2, E3, masks);

    build_both<<<4096, 256, 0, stream>>>(masks, E, ET);

    gemm_ep<<<1056, 256, 0, stream>>>(E, ET, Pt, P1, Nt, N1, (float*)d_out);
}